// Round 1
// baseline (1178.517 us; speedup 1.0000x reference)
//
#include <hip/hip_runtime.h>
#include <math.h>

// VQ quantizer: z [65536, 256] fp32, codebook [1024, 256] fp32.
// Outputs flat: z_q [16777216] | loss [1] | indices [65536] (as float values).
//
// Numerics contract (must match numpy reference to avoid argmin flips):
//   A_t = sum(z_t^2)  -- numpy pairwise order (8-acc chains, 128-blocks, fixed tree)
//   B_n = sum(e_n^2)  -- same
//   d   = fl( fl(A+B) - 2*M ),  M = fp32 fma-accumulated dot
//   argmin: first (lowest-index) minimum wins, strict < scan + lexicographic merge
//   z_q_out = fl( z + fl(e - z) )   (straight-through, two fp32 roundings)
//   loss    = fl( mf + fl(10*mf) ), mf = (float)(sum((e-z)^2)/16777216)

#define NTOK     65536
#define DDIM     256
#define NCODE    1024
#define LOSS_OFF 16777216
#define IDX_OFF  16777217

// ---------------- kernel 1: B_n = numpy-pairwise sum of squares of codebook rows;
// also zero the fp64 loss accumulator in workspace.
__global__ void vq_b_kernel(const float* __restrict__ cb, float* __restrict__ wsB,
                            double* __restrict__ loss_acc)
{
#pragma clang fp contract(off)
    int row = blockIdx.x * blockDim.x + threadIdx.x;
    if (blockIdx.x == 0 && threadIdx.x == 0) *loss_acc = 0.0;
    if (row >= NCODE) return;
    const float* a = cb + row * DDIM;
    float half[2];
    for (int h = 0; h < 2; ++h) {
        const float* b = a + h * 128;
        float r[8];
#pragma unroll
        for (int j = 0; j < 8; ++j) { float v = b[j]; r[j] = v * v; }
        for (int i = 8; i < 128; i += 8) {
#pragma unroll
            for (int j = 0; j < 8; ++j) { float v = b[i + j]; float s = v * v; r[j] = r[j] + s; }
        }
        half[h] = ((r[0] + r[1]) + (r[2] + r[3])) + ((r[4] + r[5]) + (r[6] + r[7]));
    }
    wsB[row] = half[0] + half[1];
}

// ---------------- kernel 2: main distance-argmin GEMM + gather + loss partials.
// 512 blocks x 256 threads; block owns 128 tokens vs all 1024 codes.
// Thread grid 16x16: thread (tx,ty) owns tokens {4ty+i, 64+4ty+i} and codes {4tx+j, 64+4tx+j}.
__global__ __launch_bounds__(256, 2) void vq_main(const float* __restrict__ z,
                                                  const float* __restrict__ cb,
                                                  const float* __restrict__ wsB,
                                                  double* __restrict__ loss_acc,
                                                  float* __restrict__ out)
{
    __shared__ float zs[32][128];   // [k][token]   16 KB
    __shared__ float es[32][128];   // [k][code]    16 KB
    __shared__ float Bl[1024];      //              4 KB
    __shared__ float sA[128][2];    // per-token half sums (numpy pairwise halves)
    __shared__ double lred[4];

    const int tid = threadIdx.x;
    const int tx = tid & 15, ty = tid >> 4;
    const int t0 = blockIdx.x * 128;

    // prologue: stage B into LDS (first __syncthreads below orders it vs reads)
#pragma unroll
    for (int s = 0; s < 4; ++s) Bl[tid + 256 * s] = wsB[tid + 256 * s];

    float best[8];
    int   bidx[8];
    float Aval[8];
#pragma unroll
    for (int i = 0; i < 8; ++i) { best[i] = __builtin_inff(); bidx[i] = 0x7fffffff; }

    // numpy-pairwise chains for A: thread -> (token = tid>>1, half = tid&1)
    float r[8];
#pragma unroll
    for (int j = 0; j < 8; ++j) r[j] = 0.0f;
    const int atok = tid >> 1, ah = tid & 1;

    float4 zr[4], er[4];

#define STAGE_LOAD(nc_, kc_)                                                      \
    {                                                                             \
        const float* zb_ = z  + (size_t)t0 * DDIM + (kc_) * 32;                   \
        const float* eb_ = cb + (size_t)(nc_) * 128 * DDIM + (kc_) * 32;          \
        _Pragma("unroll")                                                         \
        for (int s_ = 0; s_ < 4; ++s_) {                                          \
            int g_ = tid + 256 * s_; int row_ = g_ >> 3; int c4_ = g_ & 7;        \
            zr[s_] = *(const float4*)(zb_ + row_ * DDIM + c4_ * 4);               \
            er[s_] = *(const float4*)(eb_ + row_ * DDIM + c4_ * 4);               \
        }                                                                         \
    }

    for (int nc = 0; nc < 8; ++nc) {
        float acc[8][8];
#pragma unroll
        for (int i = 0; i < 8; ++i)
#pragma unroll
            for (int j = 0; j < 8; ++j) acc[i][j] = 0.0f;

        STAGE_LOAD(nc, 0);

        for (int kc = 0; kc < 8; ++kc) {
            __syncthreads();
            // transpose-write staged regs into LDS: zs[k][t], es[k][n]
#pragma unroll
            for (int s = 0; s < 4; ++s) {
                int g = tid + 256 * s; int row = g >> 3; int c4 = g & 7;
                zs[c4 * 4 + 0][row] = zr[s].x; zs[c4 * 4 + 1][row] = zr[s].y;
                zs[c4 * 4 + 2][row] = zr[s].z; zs[c4 * 4 + 3][row] = zr[s].w;
                es[c4 * 4 + 0][row] = er[s].x; es[c4 * 4 + 1][row] = er[s].y;
                es[c4 * 4 + 2][row] = er[s].z; es[c4 * 4 + 3][row] = er[s].w;
            }
            __syncthreads();
            if (kc < 7) STAGE_LOAD(nc, kc + 1);

            // fold numpy-pairwise ||z||^2 chains into the first n-pass
            if (nc == 0 && (kc >> 2) == ah) {
#pragma clang fp contract(off)
#pragma unroll
                for (int g = 0; g < 4; ++g)
#pragma unroll
                    for (int j = 0; j < 8; ++j) {
                        float v = zs[g * 8 + j][atok];
                        float s2 = v * v;            // square rounded to fp32 (numpy z**2)
                        r[j] = r[j] + s2;            // chain add, no fma contraction
                    }
            }

            // 32 k-steps: 4 x ds_read_b128 + 64 fp32 FMA per thread per step
#pragma unroll
            for (int k = 0; k < 32; ++k) {
                float4 a0 = *(const float4*)&zs[k][4 * ty];
                float4 a1 = *(const float4*)&zs[k][64 + 4 * ty];
                float4 b0 = *(const float4*)&es[k][4 * tx];
                float4 b1 = *(const float4*)&es[k][64 + 4 * tx];
                float za[8] = {a0.x, a0.y, a0.z, a0.w, a1.x, a1.y, a1.z, a1.w};
                float eb[8] = {b0.x, b0.y, b0.z, b0.w, b1.x, b1.y, b1.z, b1.w};
#pragma unroll
                for (int i = 0; i < 8; ++i)
#pragma unroll
                    for (int j = 0; j < 8; ++j)
                        acc[i][j] = __builtin_fmaf(za[i], eb[j], acc[i][j]);
            }
        }

        if (nc == 0) {
            // numpy combine tree per half, exchange halves, A = half0 + half1
            float s = ((r[0] + r[1]) + (r[2] + r[3])) + ((r[4] + r[5]) + (r[6] + r[7]));
            sA[atok][ah] = s;
            __syncthreads();
#pragma unroll
            for (int i = 0; i < 8; ++i) {
                int tl = (i < 4) ? (4 * ty + i) : (64 + 4 * ty + (i - 4));
                Aval[i] = sA[tl][0] + sA[tl][1];
            }
        }

        // epilogue: d = fl(fl(A+B) - 2*M), running first-min (ascending n, strict <)
#pragma unroll
        for (int i = 0; i < 8; ++i) {
#pragma unroll
            for (int j = 0; j < 8; ++j) {
                int cl = (j < 4) ? (4 * tx + j) : (64 + 4 * tx + (j - 4));
                int n = nc * 128 + cl;
                float t1 = Aval[i] + Bl[n];
                float dist = t1 - 2.0f * acc[i][j];  // 2*acc exact; single rounding
                if (dist < best[i]) { best[i] = dist; bidx[i] = n; }
            }
        }
    }

    // cross-thread lexicographic (dist, idx) min over the 16 tx-threads per token
#pragma unroll
    for (int i = 0; i < 8; ++i) {
        float d = best[i]; int w = bidx[i];
        for (int off = 8; off; off >>= 1) {
            float od = __shfl_xor(d, off);
            int   ow = __shfl_xor(w, off);
            if (od < d || (od == d && ow < w)) { d = od; w = ow; }
        }
        best[i] = d; bidx[i] = w;
    }

    // outputs: z_q rows (16 threads cooperate per token, 16 floats each), idx, loss partial
    double ld = 0.0;
#pragma unroll
    for (int i = 0; i < 8; ++i) {
        int tl = (i < 4) ? (4 * ty + i) : (64 + 4 * ty + (i - 4));
        int t = t0 + tl;
        int w = bidx[i];
        const float4* crow = (const float4*)(cb + (size_t)w * DDIM);
        const float4* zrow = (const float4*)(z + (size_t)t * DDIM);
        float4* orow = (float4*)(out + (size_t)t * DDIM);
#pragma unroll
        for (int q = 0; q < 4; ++q) {
            int c4 = tx * 4 + q;
            float4 e4 = crow[c4];
            float4 z4 = zrow[c4];
            float4 o;
            float dx;
            dx = e4.x - z4.x; o.x = z4.x + dx; ld += (double)(dx * dx);
            dx = e4.y - z4.y; o.y = z4.y + dx; ld += (double)(dx * dx);
            dx = e4.z - z4.z; o.z = z4.z + dx; ld += (double)(dx * dx);
            dx = e4.w - z4.w; o.w = z4.w + dx; ld += (double)(dx * dx);
            orow[c4] = o;
        }
        if (tx == 0) out[IDX_OFF + t] = (float)w;
    }

    // loss reduction: wave shfl -> LDS -> one double atomicAdd per block
    for (int off = 32; off; off >>= 1) ld += __shfl_down(ld, off);
    int lane = tid & 63, wv = tid >> 6;
    if (lane == 0) lred[wv] = ld;
    __syncthreads();
    if (tid == 0) {
        double s = (lred[0] + lred[1]) + (lred[2] + lred[3]);
        atomicAdd(loss_acc, s);
    }
#undef STAGE_LOAD
}

// ---------------- kernel 3: finalize loss = fl(mf + fl(10*mf))
__global__ void vq_finish(const double* __restrict__ loss_acc, float* __restrict__ out)
{
#pragma clang fp contract(off)
    double m = *loss_acc / 16777216.0;
    float mf = (float)m;
    float second = 10.0f * mf;
    out[LOSS_OFF] = mf + second;
}

extern "C" void kernel_launch(void* const* d_in, const int* in_sizes, int n_in,
                              void* d_out, int out_size, void* d_ws, size_t ws_size,
                              hipStream_t stream)
{
    (void)in_sizes; (void)n_in; (void)out_size; (void)ws_size;
    const float* z  = (const float*)d_in[0];
    const float* cb = (const float*)d_in[1];
    float* out = (float*)d_out;
    double* loss_acc = (double*)d_ws;                    // 8 B
    float* wsB = (float*)((char*)d_ws + 64);             // 4 KB, aligned

    vq_b_kernel<<<dim3(4), dim3(256), 0, stream>>>(cb, wsB, loss_acc);
    vq_main<<<dim3(NTOK / 128), dim3(256), 0, stream>>>(z, cb, wsB, loss_acc, out);
    vq_finish<<<dim3(1), dim3(1), 0, stream>>>(loss_acc, out);
}